// Round 6
// baseline (415.289 us; speedup 1.0000x reference)
//
#include <hip/hip_runtime.h>

// Trilinear forward-splat (R4 single-phase) + DS-atomic microprobes.
// Reference semantics (exact):
//   locs = max(grid + flow, 0)
//   delta = locs - floor(locs)           (from UNclamped floor)
//   base  = min((int)floor(locs), dim-1)
//   corner per axis = min(base + {0,1}, dim-1)   (collapsed corners add twice)
//
// Probe rationale: scatter-phase ds_add_f32 is the suspected wall
// (~2.5-3.3 cyc/lane fit). P0-P3 measure ds_write vs ds_add_f32 (cf/same-addr)
// vs ds_add_u32 per-dispatch via rocprof. They touch only ws -> correctness
// unaffected; dur_us inflates by probe time this round only.

constexpr int H = 192, W = 192, Dd = 192;
constexpr int N = H * W * Dd;
constexpr int WD = W * Dd;

constexpr int BI = 8, BJ = 8, BK = 64;       // source chunk per block
constexpr int HL = 2;                        // halo radius
constexpr int TI = BI + 2 * HL;              // 12
constexpr int TJ = BJ + 2 * HL;              // 12
constexpr int TK = BK + 2 * HL;              // 68
constexpr int TCELLS = TI * TJ * TK;         // 9792 floats = 38.25 KB

__global__ __launch_bounds__(512, 8) void splat_lds_kernel(const float* __restrict__ src,
                                                           const float* __restrict__ flow,
                                                           float* __restrict__ out) {
    __shared__ __align__(16) float tile[TCELLS];

    const int t  = threadIdx.x;
    const int bk = blockIdx.x, bj = blockIdx.y, bi = blockIdx.z;
    const int i0 = bi * BI, j0 = bj * BJ, k0 = bk * BK;
    const int xg0 = i0 - HL, yg0 = j0 - HL, zg0 = k0 - HL;  // tile origin (global)

    {
        const float4 z4 = make_float4(0.f, 0.f, 0.f, 0.f);
        float4* t4 = reinterpret_cast<float4*>(tile);
        for (int c = t; c < TCELLS / 4; c += 512) t4[c] = z4;
    }
    __syncthreads();

#pragma unroll
    for (int p = 0; p < 2; ++p) {
        const int g  = p * 512 + t;            // float4-group index, 0..1023
        const int kg = (g & 15) * 4;           // 0..60
        const int cj = (g >> 4) & 7;
        const int ci = g >> 7;                 // 0..7
        const int i = i0 + ci, j = j0 + cj, k = k0 + kg;
        const int off = i * WD + j * Dd + k;

        const float4 s4  = *reinterpret_cast<const float4*>(src + off);
        const float4 fx4 = *reinterpret_cast<const float4*>(flow + off);
        const float4 fy4 = *reinterpret_cast<const float4*>(flow + N + off);
        const float4 fz4 = *reinterpret_cast<const float4*>(flow + 2 * N + off);

        const float sa[4]  = {s4.x, s4.y, s4.z, s4.w};
        const float fxa[4] = {fx4.x, fx4.y, fx4.z, fx4.w};
        const float fya[4] = {fy4.x, fy4.y, fy4.z, fy4.w};
        const float fza[4] = {fz4.x, fz4.y, fz4.z, fz4.w};

#pragma unroll
        for (int q = 0; q < 4; ++q) {
            const float lx = fmaxf((float)i       + fxa[q], 0.0f);
            const float ly = fmaxf((float)j       + fya[q], 0.0f);
            const float lz = fmaxf((float)(k + q) + fza[q], 0.0f);

            const float bx = floorf(lx), by = floorf(ly), bz = floorf(lz);
            const float dx = lx - bx,    dy = ly - by,    dz = lz - bz;

            const int x0 = min((int)bx, H - 1);
            const int y0 = min((int)by, W - 1);
            const int z0 = min((int)bz, Dd - 1);
            const int x1 = min(x0 + 1, H - 1);
            const int y1 = min(y0 + 1, W - 1);
            const int z1 = min(z0 + 1, Dd - 1);

            const float s = sa[q];
            const float wx0 = 1.0f - dx, wy0 = 1.0f - dy, wz0 = 1.0f - dz;
            const float a00 = s * wx0 * wy0;
            const float a01 = s * wx0 * dy;
            const float a10 = s * dx * wy0;
            const float a11 = s * dx * dy;

            const float v000 = a00 * wz0, v001 = a00 * dz;
            const float v010 = a01 * wz0, v011 = a01 * dz;
            const float v100 = a10 * wz0, v101 = a10 * dz;
            const float v110 = a11 * wz0, v111 = a11 * dz;

            const int a0 = x0 - xg0, a1 = x1 - xg0;
            const int b0 = y0 - yg0, b1 = y1 - yg0;
            const int c0 = z0 - zg0, c1 = z1 - zg0;

            const bool fast = ((unsigned)a0 < (unsigned)TI) & ((unsigned)a1 < (unsigned)TI) &
                              ((unsigned)b0 < (unsigned)TJ) & ((unsigned)b1 < (unsigned)TJ) &
                              ((unsigned)c0 < (unsigned)TK) & ((unsigned)c1 < (unsigned)TK);

            if (__builtin_expect(fast, 1)) {
                const int r00 = (a0 * TJ + b0) * TK;
                const int r01 = (a0 * TJ + b1) * TK;
                const int r10 = (a1 * TJ + b0) * TK;
                const int r11 = (a1 * TJ + b1) * TK;
                atomicAdd(&tile[r00 + c0], v000);
                atomicAdd(&tile[r00 + c1], v001);
                atomicAdd(&tile[r01 + c0], v010);
                atomicAdd(&tile[r01 + c1], v011);
                atomicAdd(&tile[r10 + c0], v100);
                atomicAdd(&tile[r10 + c1], v101);
                atomicAdd(&tile[r11 + c0], v110);
                atomicAdd(&tile[r11 + c1], v111);
            } else {
                const int   xs[2] = {x0, x1}, ys[2] = {y0, y1}, zs[2] = {z0, z1};
                const float vs[8] = {v000, v001, v010, v011, v100, v101, v110, v111};
#pragma unroll
                for (int c = 0; c < 8; ++c) {
                    const int xx = xs[(c >> 2) & 1], yy = ys[(c >> 1) & 1], zz = zs[c & 1];
                    const int ta = xx - xg0, tb = yy - yg0, tc = zz - zg0;
                    if (((unsigned)ta < (unsigned)TI) & ((unsigned)tb < (unsigned)TJ) &
                        ((unsigned)tc < (unsigned)TK)) {
                        atomicAdd(&tile[(ta * TJ + tb) * TK + tc], vs[c]);
                    } else {
                        unsafeAtomicAdd(out + xx * WD + yy * Dd + zz, vs[c]);
                    }
                }
            }
        }
    }
    __syncthreads();

    for (int c = t; c < TCELLS; c += 512) {
        const float v = tile[c];
        if (v != 0.0f) {
            const int tk = c % TK;
            const int rest = c / TK;
            const int tj = rest % TJ;
            const int ti = rest / TJ;
            const int x = xg0 + ti, y = yg0 + tj, z = zg0 + tk;
            if (((unsigned)x < (unsigned)H) & ((unsigned)y < (unsigned)W) &
                ((unsigned)z < (unsigned)Dd)) {
                unsafeAtomicAdd(out + x * WD + y * Dd + z, v);
            }
        }
    }
}

// ---------------- DS microprobes (write results to ws; correctness-neutral) --
// MODE 0: ds_write_b32 conflict-free      (calibration)
// MODE 1: ds_add_f32  conflict-free
// MODE 2: ds_add_f32  wave-uniform addr   (max contention)
// MODE 3: ds_add_u32  conflict-free
template <int MODE>
__global__ __launch_bounds__(512) void ds_probe(float* __restrict__ ws) {
    __shared__ float buf[4096];  // 16 KB
    const int t = threadIdx.x;
    for (int c = t; c < 4096; c += 512) buf[c] = 0.f;
    __syncthreads();

    const int lane = t & 63;
    const int wv   = t >> 6;                 // 8 waves, disjoint 512-float slabs
    const float    v  = 1.0f + (float)lane * 0.001f;
    const unsigned uv = 1u + (unsigned)lane;

#pragma unroll 1
    for (int it = 0; it < 64; ++it) {
        const int cf = wv * 512 + ((it & 7) << 6) + lane;  // conflict-free (2 rows/bank min)
        if constexpr (MODE == 0) {
            buf[cf] = v + (float)it;
        } else if constexpr (MODE == 1) {
            atomicAdd(&buf[cf], v);
        } else if constexpr (MODE == 2) {
            atomicAdd(&buf[wv * 512 + (it & 7)], v);       // all 64 lanes same addr
        } else {
            atomicAdd(reinterpret_cast<unsigned*>(&buf[cf]), uv);
        }
    }
    __syncthreads();

    float acc = 0.f;
    for (int c = t; c < 4096; c += 512) acc += buf[c];
    ws[blockIdx.x * 512 + t] = acc;          // keep buf live
}

extern "C" void kernel_launch(void* const* d_in, const int* in_sizes, int n_in,
                              void* d_out, int out_size, void* d_ws, size_t ws_size,
                              hipStream_t stream) {
    const float* src  = (const float*)d_in[0];
    const float* flow = (const float*)d_in[1];
    float* out = (float*)d_out;

    // Harness poisons d_out once and never re-poisons between replays: zero it every call.
    hipMemsetAsync(out, 0, (size_t)N * sizeof(float), stream);

    const dim3 block(512);
    const dim3 grid(Dd / BK, W / BJ, H / BI);  // (3, 24, 24) = 1728 blocks
    splat_lds_kernel<<<grid, block, 0, stream>>>(src, flow, out);

    // Probes: 256 blocks (1/CU), 512 threads, 64 DS ops/thread.
    if (ws_size >= (size_t)256 * 512 * sizeof(float)) {
        float* ws = (float*)d_ws;
        ds_probe<0><<<256, 512, 0, stream>>>(ws);
        ds_probe<1><<<256, 512, 0, stream>>>(ws);
        ds_probe<2><<<256, 512, 0, stream>>>(ws);
        ds_probe<3><<<256, 512, 0, stream>>>(ws);
    }
}

// Round 7
// 128.713 us; speedup vs baseline: 3.2265x; 3.2265x over previous
//
#include <hip/hip_runtime.h>

// Trilinear forward-splat, z-moment LDS accumulation with packed u64 atomics.
// Reference semantics (exact):
//   locs = max(grid + flow, 0)
//   delta = locs - floor(locs)           (from UNclamped floor)
//   base  = min((int)floor(locs), dim-1)
//   corner per axis = min(base + {0,1}, dim-1)   (collapsed corners add twice)
//
// Cost model (R6 evidence): LDS atomics are ~per-lane serialized (~3 cyc/lane,
// ~200 cyc per wave-op) regardless of conflicts -> time ∝ #DS-atomic instrs.
// Transform: per xy-row deposit moments (S0 += w, S1 += w*dz) into ONE u64 bin
// (i32 fixed-point fields, borrow-compensated packing; exact modular sums).
// cell[z] = S0[z] - S1[z] + S1[z-1], applied at flush. 8 -> 4 atomics/voxel.

constexpr int H = 192, W = 192, Dd = 192;
constexpr int N = H * W * Dd;
constexpr int WD = W * Dd;

constexpr int BI = 8, BJ = 8, BK = 32;       // source chunk per block (2048 voxels)
constexpr int HL = 2;                        // halo radius
constexpr int TI = BI + 2 * HL;              // 12
constexpr int TJ = BJ + 2 * HL;              // 12
constexpr int TK = BK + 2 * HL;              // 36
constexpr int TBINS = TI * TJ * TK;          // 5184 u64 bins = 40.5 KB

constexpr float SCALE     = 1048576.0f;      // 2^20
constexpr float INV_SCALE = 1.0f / 1048576.0f;

__device__ __forceinline__ unsigned long long pack_moment(float w, float wdz) {
    const int da = (int)rintf(w * SCALE);
    const int db = (int)rintf(wdz * SCALE);
    // borrow compensation: sum over packed == (Σda) + 2^32 (Σdb)  (mod 2^64)
    return (unsigned long long)(unsigned)da |
           ((unsigned long long)(unsigned)(db - (da < 0 ? 1 : 0)) << 32);
}

__global__ __launch_bounds__(512) void splat_moment_kernel(const float* __restrict__ src,
                                                           const float* __restrict__ flow,
                                                           float* __restrict__ out) {
    __shared__ __align__(16) unsigned long long bins[TBINS];

    const int t  = threadIdx.x;
    const int bk = blockIdx.x, bj = blockIdx.y, bi = blockIdx.z;
    const int i0 = bi * BI, j0 = bj * BJ, k0 = bk * BK;
    const int xg0 = i0 - HL, yg0 = j0 - HL, zg0 = k0 - HL;  // tile origin (global)

    // --- zero bins (TBINS*8 B = 2592 float4) ---
    {
        const float4 z4 = make_float4(0.f, 0.f, 0.f, 0.f);
        float4* b4 = reinterpret_cast<float4*>(bins);
        for (int c = t; c < TBINS * 2 / 4; c += 512) b4[c] = z4;
    }
    __syncthreads();

    // --- scatter: 2048 voxels, 4 consecutive-z voxels per thread ---
    {
        const int kg = (t & 7) * 4;            // 0..28
        const int cj = (t >> 3) & 7;
        const int ci = t >> 6;                 // 0..7
        const int i = i0 + ci, j = j0 + cj, k = k0 + kg;
        const int off = i * WD + j * Dd + k;

        const float4 s4  = *reinterpret_cast<const float4*>(src + off);
        const float4 fx4 = *reinterpret_cast<const float4*>(flow + off);
        const float4 fy4 = *reinterpret_cast<const float4*>(flow + N + off);
        const float4 fz4 = *reinterpret_cast<const float4*>(flow + 2 * N + off);

        const float sa[4]  = {s4.x, s4.y, s4.z, s4.w};
        const float fxa[4] = {fx4.x, fx4.y, fx4.z, fx4.w};
        const float fya[4] = {fy4.x, fy4.y, fy4.z, fy4.w};
        const float fza[4] = {fz4.x, fz4.y, fz4.z, fz4.w};

#pragma unroll
        for (int q = 0; q < 4; ++q) {
            const float lx = fmaxf((float)i       + fxa[q], 0.0f);
            const float ly = fmaxf((float)j       + fya[q], 0.0f);
            const float lz = fmaxf((float)(k + q) + fza[q], 0.0f);

            const float bx = floorf(lx), by = floorf(ly), bz = floorf(lz);
            const float dx = lx - bx,    dy = ly - by,    dz = lz - bz;

            const int x0 = min((int)bx, H - 1);
            const int y0 = min((int)by, W - 1);
            const int z0 = min((int)bz, Dd - 1);
            const int x1 = min(x0 + 1, H - 1);
            const int y1 = min(y0 + 1, W - 1);
            const int z1 = min(z0 + 1, Dd - 1);

            const float s = sa[q];
            const float wx0 = 1.0f - dx, wy0 = 1.0f - dy;
            const float a00 = s * wx0 * wy0;
            const float a01 = s * wx0 * dy;
            const float a10 = s * dx * wy0;
            const float a11 = s * dx * dy;

            // z-collapse at the global boundary: both z-corners hit cell z0.
            // Moments with dzf=0 deposit the full row weight into cell z0.
            const float dzf = (z1 > z0) ? dz : 0.0f;

            const int a0 = x0 - xg0, a1 = x1 - xg0;
            const int b0 = y0 - yg0, b1 = y1 - yg0;
            const int c0 = z0 - zg0;

            const bool fast = ((unsigned)a0 < (unsigned)TI) & ((unsigned)a1 < (unsigned)TI) &
                              ((unsigned)b0 < (unsigned)TJ) & ((unsigned)b1 < (unsigned)TJ) &
                              ((unsigned)c0 < (unsigned)(TK - 1));

            if (__builtin_expect(fast, 1)) {
                atomicAdd(&bins[(a0 * TJ + b0) * TK + c0], pack_moment(a00, a00 * dzf));
                atomicAdd(&bins[(a0 * TJ + b1) * TK + c0], pack_moment(a01, a01 * dzf));
                atomicAdd(&bins[(a1 * TJ + b0) * TK + c0], pack_moment(a10, a10 * dzf));
                atomicAdd(&bins[(a1 * TJ + b1) * TK + c0], pack_moment(a11, a11 * dzf));
            } else {
                // rare outlier: direct global f32 atomics (exact corner semantics)
                const float v000 = a00 * (1.0f - dz), v001 = a00 * dz;
                const float v010 = a01 * (1.0f - dz), v011 = a01 * dz;
                const float v100 = a10 * (1.0f - dz), v101 = a10 * dz;
                const float v110 = a11 * (1.0f - dz), v111 = a11 * dz;
                unsafeAtomicAdd(out + x0 * WD + y0 * Dd + z0, v000);
                unsafeAtomicAdd(out + x0 * WD + y0 * Dd + z1, v001);
                unsafeAtomicAdd(out + x0 * WD + y1 * Dd + z0, v010);
                unsafeAtomicAdd(out + x0 * WD + y1 * Dd + z1, v011);
                unsafeAtomicAdd(out + x1 * WD + y0 * Dd + z0, v100);
                unsafeAtomicAdd(out + x1 * WD + y0 * Dd + z1, v101);
                unsafeAtomicAdd(out + x1 * WD + y1 * Dd + z0, v110);
                unsafeAtomicAdd(out + x1 * WD + y1 * Dd + z1, v111);
            }
        }
    }
    __syncthreads();

    // --- flush: cell[z] = S0[z] - S1[z] + S1[z-1]; one f32 atomic per nonzero ---
    for (int c = t; c < TBINS; c += 512) {
        const int z    = c % TK;
        const int rest = c / TK;
        const int b    = rest % TJ;
        const int a    = rest / TJ;

        const unsigned long long T  = bins[c];
        const unsigned long long Tm = (z > 0) ? bins[c - 1] : 0ull;

        const int A  = (int)(unsigned)T;                      // S0[z]
        const int B  = (int)(unsigned)(T >> 32) + (A < 0);    // S1[z]
        const int Am = (int)(unsigned)Tm;
        const int Bm = (int)(unsigned)(Tm >> 32) + (Am < 0);  // S1[z-1]

        const int vi = A - B + Bm;
        if (vi != 0) {
            const int x = xg0 + a, y = yg0 + b, zz = zg0 + z;
            if (((unsigned)x < (unsigned)H) & ((unsigned)y < (unsigned)W) &
                ((unsigned)zz < (unsigned)Dd)) {
                unsafeAtomicAdd(out + x * WD + y * Dd + zz, (float)vi * INV_SCALE);
            }
        }
    }
}

extern "C" void kernel_launch(void* const* d_in, const int* in_sizes, int n_in,
                              void* d_out, int out_size, void* d_ws, size_t ws_size,
                              hipStream_t stream) {
    const float* src  = (const float*)d_in[0];
    const float* flow = (const float*)d_in[1];
    float* out = (float*)d_out;

    // Harness poisons d_out once and never re-poisons between replays: zero it every call.
    hipMemsetAsync(out, 0, (size_t)N * sizeof(float), stream);

    const dim3 block(512);
    const dim3 grid(Dd / BK, W / BJ, H / BI);  // (6, 24, 24) = 3456 blocks
    splat_moment_kernel<<<grid, block, 0, stream>>>(src, flow, out);
}